// Round 4
// baseline (381.569 us; speedup 1.0000x reference)
//
#include <hip/hip_runtime.h>

// MaskedAttention: B=4,S=1024,W=1024,H=16,DH=64. Softmax over HEAD axis.
// cvt->bf16; QKV GEMM (m97-style global_load_lds staging, V stored [d][s]);
// qksm: QK^T + in-register 16-way head softmax -> P in block-owned layout
// [bh][kt4][qloc][kloc256]; pv: batched GEMM P@V; out-proj GEMM.
// P processed in two q-halves (pws 64MB reused), total ws 112MB.

typedef float f32x4 __attribute__((ext_vector_type(4)));
typedef __bf16 bf16x8 __attribute__((ext_vector_type(8)));

__device__ __forceinline__ unsigned short f2bf(float f){
  unsigned int u = __builtin_bit_cast(unsigned int, f);
  u = (u + 0x7FFFu + ((u >> 16) & 1u)) >> 16;
  return (unsigned short)u;
}

// async global->LDS, 16B per lane; LDS dest = wave-uniform base + lane*16
__device__ __forceinline__ void gl16(const unsigned short* g, unsigned short* l){
  __builtin_amdgcn_global_load_lds(
      (const __attribute__((address_space(1))) void*)g,
      (__attribute__((address_space(3))) void*)l, 16, 0, 0);
}

__global__ __launch_bounds__(256) void cvt_kernel(const float* __restrict__ s,
                                                  unsigned short* __restrict__ d, int n4){
  int i = blockIdx.x * 256 + threadIdx.x;
  if (i < n4){
    float4 v = ((const float4*)s)[i];
    ushort4 o;
    o.x = f2bf(v.x); o.y = f2bf(v.y); o.z = f2bf(v.z); o.w = f2bf(v.w);
    ((ushort4*)d)[i] = o;
  }
}

// all four weight matrices (1M floats each) in one launch
__global__ __launch_bounds__(256) void cvt4_kernel(
    const float* __restrict__ s0, const float* __restrict__ s1,
    const float* __restrict__ s2, const float* __restrict__ s3,
    unsigned short* __restrict__ d0, unsigned short* __restrict__ d1,
    unsigned short* __restrict__ d2, unsigned short* __restrict__ d3){
  int i = blockIdx.x * 256 + threadIdx.x;   // 0..1M-1, one float4 each
  int seg = i >> 18, j = i & 262143;
  const float* s = (seg == 0) ? s0 : (seg == 1) ? s1 : (seg == 2) ? s2 : s3;
  unsigned short* d = (seg == 0) ? d0 : (seg == 1) ? d1 : (seg == 2) ? d2 : d3;
  float4 v = ((const float4*)s)[j];
  ushort4 o;
  o.x = f2bf(v.x); o.y = f2bf(v.y); o.z = f2bf(v.z); o.w = f2bf(v.w);
  ((ushort4*)d)[j] = o;
}

// ---------------- GEMM: C[m,n] = sum_k A[m,k]*Wt[n,k] (+bias) -----------------
// m97 structure: 128x128 tile, BK=32, linear LDS [128][32], global_load_lds x16B.
// MODE 0: outp[m*N+n] = acc + bias0[n] (f32). MODE 1: QKV epilogue.
template<int MODE>
__global__ __launch_bounds__(256) void gemm_bt(
    const unsigned short* __restrict__ A, const unsigned short* __restrict__ Wt,
    int M, int N, int K,
    float* __restrict__ outp,
    unsigned short* __restrict__ qws, unsigned short* __restrict__ kws,
    unsigned short* __restrict__ vws,
    const float* __restrict__ bias0, const float* __restrict__ bias1,
    const float* __restrict__ bias2)
{
  __shared__ unsigned short As_[128*32];
  __shared__ unsigned short Bs_[128*32];
  const int tid = threadIdx.x;
  const int lane = tid & 63;
  const int wid = tid >> 6;
  const int wr = wid >> 1, wc = wid & 1;
  const int m0 = blockIdx.x * 128, n0 = blockIdx.y * 128;
  const int lq = lane & 15, lg = lane >> 4;
  const int srow = (wid << 5) + (lane >> 2);   // staging row this lane covers
  const int scol = (lane & 3) << 3;            // elems
  const unsigned short* Ag = A  + (size_t)(m0 + srow)*K + scol;
  const unsigned short* Bg = Wt + (size_t)(n0 + srow)*K + scol;
  char* a_l0 = (char*)As_ + (wid << 11);       // 32 rows x 64B per wave
  char* b_l0 = (char*)Bs_ + (wid << 11);
  f32x4 acc[4][4] = {};

  for (int k0 = 0; k0 < K; k0 += 32){
    gl16(Ag + k0,                 (unsigned short*)a_l0);
    gl16(Ag + (size_t)16*K + k0,  (unsigned short*)(a_l0 + 1024));
    gl16(Bg + k0,                 (unsigned short*)b_l0);
    gl16(Bg + (size_t)16*K + k0,  (unsigned short*)(b_l0 + 1024));
    __syncthreads();
    bf16x8 af[4], wf[4];
    #pragma unroll
    for (int i = 0; i < 4; ++i){
      af[i] = *(const bf16x8*)((char*)As_ + ((((wr<<6)+(i<<4)+lq)) << 6) + (lg << 4));
      wf[i] = *(const bf16x8*)((char*)Bs_ + ((((wc<<6)+(i<<4)+lq)) << 6) + (lg << 4));
    }
    #pragma unroll
    for (int i = 0; i < 4; ++i)
      #pragma unroll
      for (int j = 0; j < 4; ++j)
        acc[i][j] = __builtin_amdgcn_mfma_f32_16x16x32_bf16(af[i], wf[j], acc[i][j], 0, 0, 0);
    __syncthreads();
  }

  if (MODE == 0){
    #pragma unroll
    for (int j = 0; j < 4; ++j){
      int ncol = n0 + wc*64 + j*16 + lq;
      float bv = bias0[ncol];
      #pragma unroll
      for (int i = 0; i < 4; ++i){
        int mrow = m0 + wr*64 + i*16 + lg*4;
        #pragma unroll
        for (int r = 0; r < 4; ++r)
          outp[(size_t)(mrow + r)*N + ncol] = acc[i][j][r] + bv;
      }
    }
  } else {
    const int sel = n0 >> 10;   // uniform per block: 0=Q 1=K 2=V
    const float* bp = (sel == 0) ? bias0 : ((sel == 1) ? bias1 : bias2);
    #pragma unroll
    for (int j = 0; j < 4; ++j){
      int n  = n0 + wc*64 + j*16 + lq;
      int n1 = n & 1023;
      int h = n1 >> 6, d = n1 & 63;
      float bv = bp[n1];
      #pragma unroll
      for (int i = 0; i < 4; ++i){
        int mbase = m0 + wr*64 + i*16 + lg*4;
        #pragma unroll
        for (int r = 0; r < 4; ++r){
          int m = mbase + r;
          int b = m >> 10, s = m & 1023;
          unsigned short o = f2bf(acc[i][j][r] + bv);
          if (sel == 0)      qws[(size_t)((((b<<4) + h)<<10) + s)*64 + d] = o;
          else if (sel == 1) kws[(size_t)((((b<<4) + h)<<10) + s)*64 + d] = o;
          else               vws[(size_t)((((b<<4) + h)<<6) + d)*1024 + s] = o;
        }
      }
    }
  }
}

// ---------------- qksm: QK^T + head-softmax -> P (block-owned layout) --------
// grid (kt=4, qt=32, b=4) = 512 blocks, 8 waves, LDS 32KB (Q only), no loop
// barriers. P layout: pws[b][h][kt][qloc(<512)][kloc(256)] bf16; a block owns
// the contiguous 8KB region (16 q rows x 512B) -> full-line L2 write-combining.
__global__ __launch_bounds__(512, 4) void qksm_kernel(
    const unsigned short* __restrict__ qws, const unsigned short* __restrict__ kws,
    const int* __restrict__ mask, unsigned short* __restrict__ pws, int qbase)
{
  __shared__ unsigned short Qs[16*16*64];   // [16h][16q][64d], swz ((q&7)<<4)
  const int tid = threadIdx.x;
  const int lane = tid & 63, w = tid >> 6;
  const int kt = blockIdx.x, qt = blockIdx.y, b = blockIdx.z;
  const int q0 = qbase + (qt << 4);
  const int lq = lane & 15, lg = lane >> 4;
  const int aswz = (lq & 7) << 4;

  for (int c = tid; c < 2048; c += 512){
    int e = c << 3;
    int h = e >> 10, q = (e >> 6) & 15, d0 = e & 63;
    uint4 v = *(const uint4*)(qws + (size_t)((((b<<4) + h)<<10) + q0 + q)*64 + d0);
    int byteoff = (((h<<10) + (q<<6) + d0) << 1) ^ ((q & 7) << 4);
    *(uint4*)((char*)Qs + byteoff) = v;
  }
  __syncthreads();

  const float kscale = 0.125f * 1.44269504f;
  for (int it = 0; it < 2; ++it){
    const int kb = (kt << 8) + (it << 7) + (w << 4);       // global k base
    const int klocal = (it << 7) + (w << 4) + lq;          // k within block chunk
    // QK^T: 16 heads x 16 k cols; lane holds (q=lg*4+r, k=lq) per head
    f32x4 sc[16];
    #pragma unroll
    for (int h = 0; h < 16; ++h){
      int abase = (h << 11) + (lq << 7) + (lg << 4);
      bf16x8 a0 = *(const bf16x8*)((const char*)Qs + ((abase     ) ^ aswz));
      bf16x8 a1 = *(const bf16x8*)((const char*)Qs + ((abase + 64) ^ aswz));
      const unsigned short* kp = kws + (size_t)((((b<<4) + h)<<10) + kb + lq)*64 + (lg<<3);
      bf16x8 kf0 = *(const bf16x8*)(kp);
      bf16x8 kf1 = *(const bf16x8*)(kp + 32);
      f32x4 s = {};
      s = __builtin_amdgcn_mfma_f32_16x16x32_bf16(a0, kf0, s, 0, 0, 0);
      s = __builtin_amdgcn_mfma_f32_16x16x32_bf16(a1, kf1, s, 0, 0, 0);
      sc[h] = s;
    }
    const int* mp = mask + (size_t)((b<<10) + q0 + (lg<<2))*1024 + kb + lq;
    #pragma unroll
    for (int r = 0; r < 4; ++r){
      const int mv = mp[r << 10];
      float mx = sc[0][r];
      #pragma unroll
      for (int h = 1; h < 16; ++h) mx = fmaxf(mx, sc[h][r]);
      float e[16]; float sum = 0.f;
      #pragma unroll
      for (int h = 0; h < 16; ++h){
        e[h] = __builtin_amdgcn_exp2f((sc[h][r] - mx) * kscale);
        sum += e[h];
      }
      const float rs = __builtin_amdgcn_rcpf(sum);
      const int qloc = (qt << 4) + (lg << 2) + r;
      unsigned short* pp = pws + (b << 23) + (kt << 17) + (qloc << 8) + klocal;
      #pragma unroll
      for (int h = 0; h < 16; ++h){
        float pv = mv ? (e[h] * rs) : 0.0625f;   // all heads masked => exactly 1/16
        pp[h << 19] = f2bf(pv);
      }
    }
  }
}

// ---------------- pv: x[q][h*64+d] = sum_k P[q,k]*V[d,k], batched (b,h) ------
// grid (qt=4, bh=64), 256 thr / 4 waves (each 32q x 64d). m97-style staging.
// A addressing absorbs P's [kt][qloc][kloc256] chunked-k layout.
__global__ __launch_bounds__(256) void pv_kernel(
    const unsigned short* __restrict__ pws, const unsigned short* __restrict__ vws,
    unsigned short* __restrict__ xbf, int qbase)
{
  __shared__ unsigned short Ps_[128*32];
  __shared__ unsigned short Vs_[64*32];
  const int tid = threadIdx.x;
  const int lane = tid & 63;
  const int wid = tid >> 6;
  const int qt = blockIdx.x, bh = blockIdx.y;
  const int b = bh >> 4, h = bh & 15;
  const int lq = lane & 15, lg = lane >> 4;
  const int arow = (wid << 5) + (lane >> 2);   // q row within 128-tile
  const int scol = (lane & 3) << 3;            // elems
  const unsigned short* Ag = pws + ((size_t)bh << 19) + (((qt << 7) + arow) << 8) + scol;
  const int brow = (wid << 4) + (lane >> 2);   // d row (0..63)
  const unsigned short* Bg = vws + ((size_t)bh << 16) + brow*1024 + scol;
  char* a_l0 = (char*)Ps_ + (wid << 11);
  char* b_l0 = (char*)Vs_ + (wid << 10);
  f32x4 acc[2][4] = {};

  for (int k0 = 0; k0 < 1024; k0 += 32){
    const int koff = ((k0 >> 8) << 17) + (k0 & 255);
    gl16(Ag + koff,              (unsigned short*)a_l0);
    gl16(Ag + koff + (16 << 8),  (unsigned short*)(a_l0 + 1024));
    gl16(Bg + k0,                (unsigned short*)b_l0);
    __syncthreads();
    bf16x8 af[2], wf[4];
    #pragma unroll
    for (int i = 0; i < 2; ++i)
      af[i] = *(const bf16x8*)((char*)Ps_ + ((((wid<<5)+(i<<4)+lq)) << 6) + (lg << 4));
    #pragma unroll
    for (int j = 0; j < 4; ++j)
      wf[j] = *(const bf16x8*)((char*)Vs_ + ((((j<<4)+lq)) << 6) + (lg << 4));
    #pragma unroll
    for (int i = 0; i < 2; ++i)
      #pragma unroll
      for (int j = 0; j < 4; ++j)
        acc[i][j] = __builtin_amdgcn_mfma_f32_16x16x32_bf16(af[i], wf[j], acc[i][j], 0, 0, 0);
    __syncthreads();
  }

  #pragma unroll
  for (int j = 0; j < 4; ++j){
    int d = (j << 4) + lq;
    #pragma unroll
    for (int i = 0; i < 2; ++i){
      #pragma unroll
      for (int r = 0; r < 4; ++r){
        int qrow = qbase + (qt << 7) + (wid << 5) + (i << 4) + (lg << 2) + r;
        xbf[(size_t)((b << 10) + qrow)*1024 + (h << 6) + d] = f2bf(acc[i][j][r]);
      }
    }
  }
}

extern "C" void kernel_launch(void* const* d_in, const int* in_sizes, int n_in,
                              void* d_out, int out_size, void* d_ws, size_t ws_size,
                              hipStream_t stream) {
  const float* inp = (const float*)d_in[0];
  const int*  mask = (const int*)d_in[1];
  const float* wq = (const float*)d_in[2];
  const float* bq = (const float*)d_in[3];
  const float* wk = (const float*)d_in[4];
  const float* bk = (const float*)d_in[5];
  const float* wv = (const float*)d_in[6];
  const float* bv = (const float*)d_in[7];
  const float* wo = (const float*)d_in[8];
  const float* bo = (const float*)d_in[9];
  float* out = (float*)d_out;

  char* ws = (char*)d_ws;
  unsigned short* inp_bf = (unsigned short*)(ws);                    // 8MB
  unsigned short* wqkv   = (unsigned short*)(ws + (8u  << 20));      // 6MB
  unsigned short* wo_bf  = (unsigned short*)(ws + (14u << 20));      // 2MB
  unsigned short* qws    = (unsigned short*)(ws + (16u << 20));      // 8MB [b][h][s][d]
  unsigned short* kws    = (unsigned short*)(ws + (24u << 20));      // 8MB [b][h][s][d]
  unsigned short* vws    = (unsigned short*)(ws + (32u << 20));      // 8MB [b][h][d][s]
  unsigned short* xbf    = (unsigned short*)(ws + (40u << 20));      // 8MB
  unsigned short* pws    = (unsigned short*)(ws + (48u << 20));      // 64MB [b][h][kt][q512][k256]

  cvt_kernel<<<4096, 256, 0, stream>>>(inp, inp_bf, 1048576);
  cvt4_kernel<<<4096, 256, 0, stream>>>(wq, wk, wv, wo,
                                        wqkv, wqkv + (1u << 20), wqkv + (2u << 20), wo_bf);

  gemm_bt<1><<<dim3(32, 24), 256, 0, stream>>>(inp_bf, wqkv, 4096, 3072, 1024,
                                               nullptr, qws, kws, vws, bq, bk, bv);

  for (int half = 0; half < 2; ++half){
    qksm_kernel<<<dim3(4, 32, 4), 512, 0, stream>>>(qws, kws, mask, pws, half * 512);
    pv_kernel<<<dim3(4, 64), 256, 0, stream>>>(pws, vws, xbf, half * 512);
  }

  gemm_bt<0><<<dim3(32, 8), 256, 0, stream>>>(xbf, wo_bf, 4096, 1024, 1024,
                                              out, nullptr, nullptr, nullptr, bo, nullptr, nullptr);
}